// Round 5
// baseline (80.426 us; speedup 1.0000x reference)
//
#include <hip/hip_runtime.h>
#include <math.h>

#define DD 256
#define NO 128
#define WT_PLANE 65536          // ushorts per (hi|lo) plane: 2*128*256
#define ORW 132                 // orb row stride in floats (2-way banks, free)
#define ORB_WAVE (16*ORW)       // floats per wave tile (16 rows)

typedef __attribute__((ext_vector_type(8))) short bf16x8;
typedef __attribute__((ext_vector_type(4))) float f32x4;

static __device__ inline unsigned short f2bf(float x) {
    unsigned int u = __float_as_uint(x);
    unsigned int r = (u + 0x7FFFu + ((u >> 16) & 1u)) >> 16;   // RN-even
    return (unsigned short)r;
}
static __device__ inline float bf2f(unsigned short h) {
    return __uint_as_float(((unsigned int)h) << 16);
}

// ---- pre-kernel: W (k-major) -> W^T (n-major, k contiguous), split bf16 hi/lo ----
__global__ void prep_wt(const float* __restrict__ Wu, const float* __restrict__ Wd,
                        unsigned short* __restrict__ wt) {
    const int n    = blockIdx.x & 127;
    const int spin = blockIdx.x >> 7;
    const float* W = spin ? Wd : Wu;
    const int t = threadIdx.x;          // 64
    for (int kk = t; kk < DD; kk += 64) {
        const float x = W[(size_t)kk * NO + n];
        const unsigned short h = f2bf(x);
        const unsigned short l = f2bf(x - bf2f(h));
        const size_t o = ((size_t)spin * NO + n) * DD + kk;
        wt[o]            = h;
        wt[WT_PLANE + o] = l;
    }
}

// 4 batches/block, 4 waves; wave = one 16-row M-tile of one spin.
__global__ __launch_bounds__(256, 4)
void fermi_main(const float* __restrict__ stream1e, const float* __restrict__ r_ei,
                const float* __restrict__ bu, const float* __restrict__ piu,
                const float* __restrict__ au, const float* __restrict__ bd,
                const float* __restrict__ pid_, const float* __restrict__ ad,
                const unsigned short* __restrict__ wt, float* __restrict__ out)
{
    __shared__ __align__(16) float orb[4 * ORB_WAVE];   // 33.8 KB
    __shared__ __align__(16) float distL[4 * 16 * 4];   // 1 KB [wave][row][ion]
    __shared__ float exL[2 * 4 * 16 * 2];               // 1 KB [sp][b][det][l,s]

    const int t    = threadIdx.x;
    const int w    = t >> 6;
    const int lane = t & 63;
    const int lr   = lane & 15;
    const int lg   = lane >> 4;
    const int sp   = w >> 1;            // wave's spin
    const int half = w & 1;             // which batch pair (0: b0,b1; 1: b2,b3)
    const int b0   = blockIdx.x * 4;

    // ---- dists for this wave's 16 rows x 4 ions (1 entry/lane) ----
    {
        const int row = lane >> 2, ion = lane & 3;
        const int b  = b0 + half * 2 + (row >> 3);
        const int ge = sp * 8 + (row & 7);
        const float* rp = r_ei + (((size_t)b * 16 + ge) * 4 + ion) * 3;
        const float x = rp[0], y = rp[1], z = rp[2];
        distL[(w * 16 + row) * 4 + ion] = sqrtf(x * x + y * y + z * z);
    }
    // same-wave produce/consume: compiler's lgkmcnt ordering suffices

    // ---- A row base for this lane's tile row (lr) ----
    const size_t arow =
        (((size_t)(b0 + half * 2 + (lr >> 3)) * 16) + sp * 8 + (lr & 7)) * DD;
    const unsigned short* wts = wt + (size_t)sp * NO * DD;

    f32x4 acc[8];
    #pragma unroll
    for (int nt = 0; nt < 8; ++nt) acc[nt] = (f32x4){0.f, 0.f, 0.f, 0.f};

    // ---- barrier-free MFMA GEMM over K=256 ----
    #pragma unroll
    for (int kt = 0; kt < 8; ++kt) {
        const int k0 = kt * 32;
        const float* ap = stream1e + arow + k0 + lg * 8;
        const float4 v0 = *(const float4*)ap;
        const float4 v1 = *(const float4*)(ap + 4);
        const float f[8] = {v0.x, v0.y, v0.z, v0.w, v1.x, v1.y, v1.z, v1.w};
        int hw[4], lw[4];
        #pragma unroll
        for (int p = 0; p < 4; ++p) {
            unsigned int hp;
            asm("v_cvt_pk_bf16_f32 %0, %1, %2" : "=v"(hp) : "v"(f[2*p]), "v"(f[2*p+1]));
            const float h0 = __uint_as_float(hp << 16);
            const float h1 = __uint_as_float(hp & 0xFFFF0000u);
            const float l0 = f[2*p]   - h0;
            const float l1 = f[2*p+1] - h1;
            unsigned int lp;
            asm("v_cvt_pk_bf16_f32 %0, %1, %2" : "=v"(lp) : "v"(l0), "v"(l1));
            hw[p] = (int)hp;
            lw[p] = (int)lp;
        }
        const bf16x8 ah = *(const bf16x8*)hw;
        const bf16x8 al = *(const bf16x8*)lw;

        #pragma unroll
        for (int nt = 0; nt < 8; ++nt) {
            const size_t off = ((size_t)(nt * 16 + lr)) * DD + k0 + lg * 8;
            const bf16x8 bh_ = *(const bf16x8*)(wts + off);
            const bf16x8 bl_ = *(const bf16x8*)(wts + WT_PLANE + off);
            acc[nt] = __builtin_amdgcn_mfma_f32_16x16x32_bf16(ah, bh_, acc[nt], 0, 0, 0);
            acc[nt] = __builtin_amdgcn_mfma_f32_16x16x32_bf16(ah, bl_, acc[nt], 0, 0, 0);
            acc[nt] = __builtin_amdgcn_mfma_f32_16x16x32_bf16(al, bh_, acc[nt], 0, 0, 0);
        }
    }

    // ---- epilogue: bias + envelope, write 16 rows to this wave's LDS tile ----
    const float* pi_s = sp ? pid_ : piu;
    const float* a_s  = sp ? ad   : au;
    const float* b_s  = sp ? bd   : bu;
    float* ow = orb + (size_t)w * ORB_WAVE;
    {
        float dq[4][4];
        #pragma unroll
        for (int q = 0; q < 4; ++q) {
            const int row = lg * 4 + q;
            const f32x4 dv = *(const f32x4*)&distL[(w * 16 + row) * 4];
            dq[q][0] = dv[0]; dq[q][1] = dv[1]; dq[q][2] = dv[2]; dq[q][3] = dv[3];
        }
        #pragma unroll
        for (int nt = 0; nt < 8; ++nt) {
            const int C = nt * 16 + lr;
            float pv[4], av[4];
            #pragma unroll
            for (int ion = 0; ion < 4; ++ion) {
                pv[ion] = pi_s[ion * NO + C];
                av[ion] = a_s [ion * NO + C];
            }
            const float bias = b_s[C];
            #pragma unroll
            for (int q = 0; q < 4; ++q) {
                float env = 0.f;
                #pragma unroll
                for (int ion = 0; ion < 4; ++ion)
                    env += pv[ion] * __expf(-av[ion] * dq[q][ion]);
                ow[(lg * 4 + q) * ORW + C] = (acc[nt][q] + bias) * env;
            }
        }
    }
    // same-wave LDS RAW: no barrier

    // ---- per-lane 8x8 slogdet (register LU, conditional-swap pivoting) ----
    if (lane < 32) {
        const int u  = lane >> 4;       // which of the wave's 2 batches
        const int dd = lane & 15;       // determinant index
        float M[8][8];
        #pragma unroll
        for (int e = 0; e < 8; ++e) {
            const float* pr = ow + (u * 8 + e) * ORW + dd * 8;
            const f32x4 u0 = *(const f32x4*)pr;
            const f32x4 u1 = *(const f32x4*)(pr + 4);
            M[e][0] = u0[0]; M[e][1] = u0[1]; M[e][2] = u0[2]; M[e][3] = u0[3];
            M[e][4] = u1[0]; M[e][5] = u1[1]; M[e][6] = u1[2]; M[e][7] = u1[3];
        }
        float ldet = 0.f, sgn = 1.f;
        #pragma unroll
        for (int c = 0; c < 8; ++c) {
            #pragma unroll
            for (int r = c + 1; r < 8; ++r) {
                const bool swp = fabsf(M[r][c]) > fabsf(M[c][c]);
                sgn = swp ? -sgn : sgn;
                #pragma unroll
                for (int j = c; j < 8; ++j) {
                    const float x1 = M[c][j], x2 = M[r][j];
                    M[c][j] = swp ? x2 : x1;
                    M[r][j] = swp ? x1 : x2;
                }
            }
            const float p = M[c][c];
            ldet += __logf(fabsf(p));
            sgn  = (p < 0.f) ? -sgn : sgn;
            const float rp = (p != 0.f) ? (1.0f / p) : 0.f;
            #pragma unroll
            for (int r = c + 1; r < 8; ++r) {
                const float fm = M[r][c] * rp;
                #pragma unroll
                for (int j = c + 1; j < 8; ++j)
                    M[r][j] = fmaf(-fm, M[c][j], M[r][j]);
            }
        }
        const int bb = half * 2 + u;    // block-local batch 0..3
        exL[((sp * 4 + bb) * 16 + dd) * 2 + 0] = ldet;
        exL[((sp * 4 + bb) * 16 + dd) * 2 + 1] = sgn;
    }
    __syncthreads();

    // ---- signed logsumexp over 16 determinants (wave 0, 16 lanes/batch) ----
    if (t < 64) {
        const int b  = t >> 4;
        const int d2 = t & 15;
        const float lu  = exL[((b)     * 16 + d2) * 2 + 0];
        const float su  = exL[((b)     * 16 + d2) * 2 + 1];
        const float ldn = exL[((4 + b) * 16 + d2) * 2 + 0];
        const float sdn = exL[((4 + b) * 16 + d2) * 2 + 1];
        const float l   = lu + ldn;
        const float s   = su * sdn;
        float m = l;
        #pragma unroll
        for (int off = 1; off <= 8; off <<= 1) m = fmaxf(m, __shfl_xor(m, off));
        float ss = s * __expf(l - m);
        #pragma unroll
        for (int off = 1; off <= 8; off <<= 1) ss += __shfl_xor(ss, off);
        if (d2 == 0) out[b0 + b] = m + __logf(fabsf(ss));
    }
}

extern "C" void kernel_launch(void* const* d_in, const int* in_sizes, int n_in,
                              void* d_out, int out_size, void* d_ws, size_t ws_size,
                              hipStream_t stream) {
    (void)n_in; (void)in_sizes; (void)ws_size;
    const float* s1e  = (const float*)d_in[0];
    const float* r_ei = (const float*)d_in[1];
    const float* Wu   = (const float*)d_in[2];
    const float* bu   = (const float*)d_in[3];
    const float* piu  = (const float*)d_in[4];
    const float* au   = (const float*)d_in[5];
    const float* Wd   = (const float*)d_in[6];
    const float* bd   = (const float*)d_in[7];
    const float* pid_ = (const float*)d_in[8];
    const float* ad   = (const float*)d_in[9];
    float* out = (float*)d_out;
    unsigned short* wt = (unsigned short*)d_ws;   // 256 KB

    hipLaunchKernelGGL(prep_wt, dim3(256), dim3(64), 0, stream, Wu, Wd, wt);

    const int B = out_size;   // 4096
    hipLaunchKernelGGL(fermi_main, dim3(B / 4), dim3(256), 0, stream,
                       s1e, r_ei, bu, piu, au, bd, pid_, ad, wt, out);
}

// Round 6
// 64.472 us; speedup vs baseline: 1.2475x; 1.2475x over previous
//
#include <hip/hip_runtime.h>
#include <math.h>

#define DD 256
#define NO 128
#define WT_PLANE 65536          // ushorts per (hi|lo) plane: 2*128*256
#define ORW 132                 // orb row stride in floats

typedef __attribute__((ext_vector_type(8))) short bf16x8;
typedef __attribute__((ext_vector_type(4))) float f32x4;

static __device__ inline unsigned short f2bf(float x) {
    unsigned int u = __float_as_uint(x);
    unsigned int r = (u + 0x7FFFu + ((u >> 16) & 1u)) >> 16;   // RN-even
    return (unsigned short)r;
}
static __device__ inline float bf2f(unsigned short h) {
    return __uint_as_float(((unsigned int)h) << 16);
}

// ---- pre-kernel: W (k-major) -> W^T (n-major, k contiguous), split bf16 hi/lo ----
__global__ void prep_wt(const float* __restrict__ Wu, const float* __restrict__ Wd,
                        unsigned short* __restrict__ wt) {
    const int n    = blockIdx.x & 127;
    const int spin = blockIdx.x >> 7;
    const float* W = spin ? Wd : Wu;
    const int t = threadIdx.x;          // 64
    for (int kk = t; kk < DD; kk += 64) {
        const float x = W[(size_t)kk * NO + n];
        const unsigned short h = f2bf(x);
        const unsigned short l = f2bf(x - bf2f(h));
        const size_t o = ((size_t)spin * NO + n) * DD + kk;
        wt[o]            = h;
        wt[WT_PLANE + o] = l;
    }
}

// Block: 4 batches, 4 waves. Wave = (spin, n-half): W-hi fragments in registers,
// W-lo + stream streamed per k-tile. D = W^T x s^T (orbitals transposed in acc).
__global__ __launch_bounds__(256, 2)
void fermi_main(const float* __restrict__ stream1e, const float* __restrict__ r_ei,
                const float* __restrict__ bu, const float* __restrict__ piu,
                const float* __restrict__ au, const float* __restrict__ bd,
                const float* __restrict__ pid_, const float* __restrict__ ad,
                const unsigned short* __restrict__ wt, float* __restrict__ out)
{
    __shared__ __align__(16) float orb[64 * ORW];      // 33 KB  [sp*32 + r][n]
    __shared__ __align__(16) float distw[4 * 32 * 4];  // 2 KB   [wave][row][ion]
    __shared__ float exL[2 * 4 * 16 * 2];              // 1 KB   [sp][b][det][l,s]

    const int t    = threadIdx.x;
    const int w    = t >> 6;
    const int lane = t & 63;
    const int lr   = lane & 15;
    const int lg   = lane >> 4;
    const int sp   = w >> 1;            // wave's spin
    const int nh   = w & 1;             // n-half (0: cols 0..63, 1: 64..127)
    const int n0   = nh * 64;
    const int b0   = blockIdx.x * 4;

    // ---- dists: per-wave private copy (32 spin-rows x 4 ions, 2/lane) ----
    #pragma unroll
    for (int i = 0; i < 2; ++i) {
        const int idx = lane * 2 + i;          // 0..127
        const int row = idx >> 2, ion = idx & 3;
        const int b  = b0 + (row >> 3);
        const int ge = sp * 8 + (row & 7);
        const float* rp = r_ei + (((size_t)b * 16 + ge) * 4 + ion) * 3;
        const float x = rp[0], y = rp[1], z = rp[2];
        distw[(w * 32 + row) * 4 + ion] = sqrtf(x * x + y * y + z * z);
    }

    // ---- W-hi fragments in registers: 4 n-tiles x 8 k-tiles (128 VGPRs) ----
    const unsigned short* wth = wt + ((size_t)sp * NO + n0) * DD;
    const unsigned short* wtl = wth + WT_PLANE;
    bf16x8 whf[4][8];
    #pragma unroll
    for (int nt = 0; nt < 4; ++nt) {
        const unsigned short* p = wth + (size_t)(nt * 16 + lr) * DD + lg * 8;
        #pragma unroll
        for (int kt = 0; kt < 8; ++kt)
            whf[nt][kt] = *(const bf16x8*)(p + kt * 32);
    }

    f32x4 acc[4][2];
    #pragma unroll
    for (int nt = 0; nt < 4; ++nt)
        #pragma unroll
        for (int rt = 0; rt < 2; ++rt)
            acc[nt][rt] = (f32x4){0.f, 0.f, 0.f, 0.f};

    // stream row bases: local spin-row r = rt*16 + lr -> batch b0 + (r>>3), el r&7
    const size_t srow0 = (((size_t)(b0     + (lr >> 3)) * 16) + sp * 8 + (lr & 7)) * DD;
    const size_t srow1 = (((size_t)(b0 + 2 + (lr >> 3)) * 16) + sp * 8 + (lr & 7)) * DD;

    // ---- barrier-free MFMA GEMM over K=256 ----
    #pragma unroll
    for (int kt = 0; kt < 8; ++kt) {
        const int k0 = kt * 32;
        bf16x8 sh[2], sl[2];
        #pragma unroll
        for (int rt = 0; rt < 2; ++rt) {
            const float* ap = stream1e + (rt ? srow1 : srow0) + k0 + lg * 8;
            const f32x4 v0 = *(const f32x4*)ap;
            const f32x4 v1 = *(const f32x4*)(ap + 4);
            const float f[8] = {v0[0], v0[1], v0[2], v0[3], v1[0], v1[1], v1[2], v1[3]};
            int hw[4], lw[4];
            #pragma unroll
            for (int p = 0; p < 4; ++p) {
                unsigned int hp;
                asm("v_cvt_pk_bf16_f32 %0, %1, %2" : "=v"(hp) : "v"(f[2*p]), "v"(f[2*p+1]));
                const float h0 = __uint_as_float(hp << 16);
                const float h1 = __uint_as_float(hp & 0xFFFF0000u);
                const float l0 = f[2*p]   - h0;
                const float l1 = f[2*p+1] - h1;
                unsigned int lp;
                asm("v_cvt_pk_bf16_f32 %0, %1, %2" : "=v"(lp) : "v"(l0), "v"(l1));
                hw[p] = (int)hp;
                lw[p] = (int)lp;
            }
            sh[rt] = *(const bf16x8*)hw;
            sl[rt] = *(const bf16x8*)lw;
        }
        bf16x8 wl[4];
        #pragma unroll
        for (int nt = 0; nt < 4; ++nt)
            wl[nt] = *(const bf16x8*)(wtl + (size_t)(nt * 16 + lr) * DD + k0 + lg * 8);

        #pragma unroll
        for (int nt = 0; nt < 4; ++nt)
            #pragma unroll
            for (int rt = 0; rt < 2; ++rt) {
                acc[nt][rt] = __builtin_amdgcn_mfma_f32_16x16x32_bf16(whf[nt][kt], sh[rt], acc[nt][rt], 0, 0, 0);
                acc[nt][rt] = __builtin_amdgcn_mfma_f32_16x16x32_bf16(whf[nt][kt], sl[rt], acc[nt][rt], 0, 0, 0);
                acc[nt][rt] = __builtin_amdgcn_mfma_f32_16x16x32_bf16(wl[nt],      sh[rt], acc[nt][rt], 0, 0, 0);
            }
    }

    // ---- epilogue: bias + envelope; acc is orb^T (row=n via lg*4+q, col=r via lr) ----
    const float* pi_s = sp ? pid_ : piu;
    const float* a_s  = sp ? ad   : au;
    const float* b_s  = sp ? bd   : bu;
    #pragma unroll
    for (int nt = 0; nt < 4; ++nt) {
        const int nb = n0 + nt * 16 + lg * 4;   // 4 consecutive n (q=0..3)
        f32x4 pv[4], av[4];
        #pragma unroll
        for (int ion = 0; ion < 4; ++ion) {
            pv[ion] = *(const f32x4*)(pi_s + ion * NO + nb);
            av[ion] = *(const f32x4*)(a_s  + ion * NO + nb);
        }
        const f32x4 bias = *(const f32x4*)(b_s + nb);
        #pragma unroll
        for (int rt = 0; rt < 2; ++rt) {
            const int r = rt * 16 + lr;         // local spin-row
            const f32x4 dv = *(const f32x4*)&distw[(w * 32 + r) * 4];
            f32x4 o;
            #pragma unroll
            for (int q = 0; q < 4; ++q) {
                const float env = pv[0][q] * __expf(-av[0][q] * dv[0])
                                + pv[1][q] * __expf(-av[1][q] * dv[1])
                                + pv[2][q] * __expf(-av[2][q] * dv[2])
                                + pv[3][q] * __expf(-av[3][q] * dv[3]);
                o[q] = (acc[nt][rt][q] + bias[q]) * env;
            }
            *(f32x4*)&orb[(size_t)(sp * 32 + r) * ORW + nb] = o;
        }
    }
    __syncthreads();   // cross-wave: both n-halves must be written before LU

    // ---- per-lane 8x8 slogdet (register LU; rotated row reads kill bank conflicts) ----
    if (lane < 32) {
        const int bloc = 2 * nh + (lane >> 4);  // block-local batch 0..3
        const int dd   = lane & 15;
        const int rot  = (lane >> 2) & 7;       // cyclic row rotation
        const float* base = orb + (size_t)(sp * 32 + bloc * 8) * ORW + dd * 8;
        float M[8][8];
        #pragma unroll
        for (int j = 0; j < 8; ++j) {
            const int e = (j + rot) & 7;
            const float* pr = base + e * ORW;
            const f32x4 u0 = *(const f32x4*)pr;
            const f32x4 u1 = *(const f32x4*)(pr + 4);
            M[j][0] = u0[0]; M[j][1] = u0[1]; M[j][2] = u0[2]; M[j][3] = u0[3];
            M[j][4] = u1[0]; M[j][5] = u1[1]; M[j][6] = u1[2]; M[j][7] = u1[3];
        }
        float ldet = 0.f, sgn = (rot & 1) ? -1.f : 1.f;   // cyclic-shift parity
        #pragma unroll
        for (int c = 0; c < 8; ++c) {
            #pragma unroll
            for (int r = c + 1; r < 8; ++r) {
                const bool swp = fabsf(M[r][c]) > fabsf(M[c][c]);
                sgn = swp ? -sgn : sgn;
                #pragma unroll
                for (int j = c; j < 8; ++j) {
                    const float x1 = M[c][j], x2 = M[r][j];
                    M[c][j] = swp ? x2 : x1;
                    M[r][j] = swp ? x1 : x2;
                }
            }
            const float p = M[c][c];
            ldet += __logf(fabsf(p));
            sgn  = (p < 0.f) ? -sgn : sgn;
            const float rp = (p != 0.f) ? (1.0f / p) : 0.f;
            #pragma unroll
            for (int r = c + 1; r < 8; ++r) {
                const float fm = M[r][c] * rp;
                #pragma unroll
                for (int j = c + 1; j < 8; ++j)
                    M[r][j] = fmaf(-fm, M[c][j], M[r][j]);
            }
        }
        exL[((sp * 4 + bloc) * 16 + dd) * 2 + 0] = ldet;
        exL[((sp * 4 + bloc) * 16 + dd) * 2 + 1] = sgn;
    }
    __syncthreads();

    // ---- signed logsumexp over 16 determinants (threads 0..63) ----
    if (t < 64) {
        const int b  = t >> 4;
        const int d2 = t & 15;
        const float lu  = exL[((b)     * 16 + d2) * 2 + 0];
        const float su  = exL[((b)     * 16 + d2) * 2 + 1];
        const float ldn = exL[((4 + b) * 16 + d2) * 2 + 0];
        const float sdn = exL[((4 + b) * 16 + d2) * 2 + 1];
        const float l   = lu + ldn;
        const float s   = su * sdn;
        float m = l;
        #pragma unroll
        for (int off = 1; off <= 8; off <<= 1) m = fmaxf(m, __shfl_xor(m, off));
        float ss = s * __expf(l - m);
        #pragma unroll
        for (int off = 1; off <= 8; off <<= 1) ss += __shfl_xor(ss, off);
        if (d2 == 0) out[b0 + b] = m + __logf(fabsf(ss));
    }
}

extern "C" void kernel_launch(void* const* d_in, const int* in_sizes, int n_in,
                              void* d_out, int out_size, void* d_ws, size_t ws_size,
                              hipStream_t stream) {
    (void)n_in; (void)in_sizes; (void)ws_size;
    const float* s1e  = (const float*)d_in[0];
    const float* r_ei = (const float*)d_in[1];
    const float* Wu   = (const float*)d_in[2];
    const float* bu   = (const float*)d_in[3];
    const float* piu  = (const float*)d_in[4];
    const float* au   = (const float*)d_in[5];
    const float* Wd   = (const float*)d_in[6];
    const float* bd   = (const float*)d_in[7];
    const float* pid_ = (const float*)d_in[8];
    const float* ad   = (const float*)d_in[9];
    float* out = (float*)d_out;
    unsigned short* wt = (unsigned short*)d_ws;   // 256 KB

    hipLaunchKernelGGL(prep_wt, dim3(256), dim3(64), 0, stream, Wu, Wd, wt);

    const int B = out_size;   // 4096
    hipLaunchKernelGGL(fermi_main, dim3(B / 4), dim3(256), 0, stream,
                       s1e, r_ei, bu, piu, au, bd, pid_, ad, wt, out);
}

// Round 7
// 36.313 us; speedup vs baseline: 2.2148x; 1.7754x over previous
//
#include <hip/hip_runtime.h>
#include <math.h>

#define DD 256
#define NO 128
#define WT_PLANE 65536          // ushorts per (hi|lo) plane: 2*128*256
#define ORW 132                 // orb row stride in floats
#define ORB_WAVE (32*ORW)       // floats per wave orb tile (32 rows)
#define UNI_US 33792            // union size in ushorts (= 4*ORB_WAVE floats = 67584 B)
#define BUF_US 16384            // one W staging buffer: 512 rows * 32 ushorts (32 KB)

typedef __attribute__((ext_vector_type(8))) short bf16x8;
typedef __attribute__((ext_vector_type(4))) float f32x4;

static __device__ inline unsigned short f2bf(float x) {
    unsigned int u = __float_as_uint(x);
    unsigned int r = (u + 0x7FFFu + ((u >> 16) & 1u)) >> 16;   // RN-even
    return (unsigned short)r;
}
static __device__ inline float bf2f(unsigned short h) {
    return __uint_as_float(((unsigned int)h) << 16);
}

// ---- pre-kernel: W (k-major) -> W^T (n-major, k contiguous), split bf16 hi/lo ----
// wt ushort layout: [pl hi|lo][spin][n(128)][k(256)]
__global__ void prep_wt(const float* __restrict__ Wu, const float* __restrict__ Wd,
                        unsigned short* __restrict__ wt) {
    const int n    = blockIdx.x & 127;
    const int spin = blockIdx.x >> 7;
    const float* W = spin ? Wd : Wu;
    const int t = threadIdx.x;          // 64
    for (int kk = t; kk < DD; kk += 64) {
        const float x = W[(size_t)kk * NO + n];
        const unsigned short h = f2bf(x);
        const unsigned short l = f2bf(x - bf2f(h));
        const size_t o = ((size_t)spin * NO + n) * DD + kk;
        wt[o]            = h;
        wt[WT_PLANE + o] = l;
    }
}

// 8 batches/block, 4 waves: wave = (spin, batch-half), 32 rows x 128 cols.
// W staged per k-tile into LDS (dbuf, coalesced); A read direct (full-line across wave).
__global__ __launch_bounds__(256, 2)
void fermi_main(const float* __restrict__ stream1e, const float* __restrict__ r_ei,
                const float* __restrict__ bu, const float* __restrict__ piu,
                const float* __restrict__ au, const float* __restrict__ bd,
                const float* __restrict__ pid_, const float* __restrict__ ad,
                const unsigned short* __restrict__ wt, float* __restrict__ out)
{
    __shared__ __align__(16) unsigned short uni[UNI_US];  // 67.6 KB: W dbuf | orb
    __shared__ __align__(16) float distL[4 * 32 * 4];     // 2 KB [wave][row][ion]
    __shared__ float exL[2 * 8 * 16 * 2];                 // 2 KB [sp][b][det][l,s]

    float* orb = (float*)uni;

    const int t    = threadIdx.x;
    const int w    = t >> 6;
    const int lane = t & 63;
    const int lr   = lane & 15;
    const int lg   = lane >> 4;
    const int sp   = w >> 1;            // wave's spin
    const int bh   = w & 1;             // batch half (0: b0..3, 1: b4..7)
    const int b0   = blockIdx.x * 8;

    // ---- dists for this wave's 32 rows x 4 ions (2 entries/lane) ----
    #pragma unroll
    for (int i = 0; i < 2; ++i) {
        const int idx = lane * 2 + i;           // 0..127
        const int row = idx >> 2, ion = idx & 3;
        const int b  = b0 + bh * 4 + (row >> 3);
        const int ge = sp * 8 + (row & 7);
        const float* rp = r_ei + (((size_t)b * 16 + ge) * 4 + ion) * 3;
        const float x = rp[0], y = rp[1], z = rp[2];
        distL[(w * 32 + row) * 4 + ion] = sqrtf(x * x + y * y + z * z);
    }
    // same-wave produce/consume: no barrier needed

    // ---- A row bases ----
    size_t arow0, arow1;
    {
        const int r0 = lr;
        const int r1 = 16 + lr;
        arow0 = (((size_t)(b0 + bh * 4 + (r0 >> 3)) * 16) + sp * 8 + (r0 & 7)) * DD;
        arow1 = (((size_t)(b0 + bh * 4 + (r1 >> 3)) * 16) + sp * 8 + (r1 & 7)) * DD;
    }

    // ---- W stage: 2048 uint4 per k-tile (512 rows x 32 ushorts), slot-rotated ----
    // LDS row = pl*256 + sp*128 + n  (matches wt's plane-major order linearly)
    auto stage = [&](int buf, int kt) {
        const int k0 = kt * 32;
        #pragma unroll
        for (int i = 0; i < 8; ++i) {
            const int idx  = i * 256 + t;      // 0..2047
            const int row  = idx >> 2;         // 0..511
            const int slot = idx & 3;
            const uint4 v = *(const uint4*)(wt + (size_t)(row >> 8) * WT_PLANE
                                               + (size_t)(row & 255) * DD + k0 + slot * 8);
            *(uint4*)(uni + buf * BUF_US + row * 32 + ((slot + row) & 3) * 8) = v;
        }
    };

    f32x4 acc[2][8];
    #pragma unroll
    for (int mt = 0; mt < 2; ++mt)
        #pragma unroll
        for (int nt = 0; nt < 8; ++nt)
            acc[mt][nt] = (f32x4){0.f, 0.f, 0.f, 0.f};

    stage(0, 0);
    __syncthreads();

    // ---- MFMA GEMM over K=256, W double-buffered through LDS ----
    for (int kt = 0; kt < 8; ++kt) {
        if (kt < 7) stage((kt + 1) & 1, kt + 1);   // issue next tile early

        const int k0 = kt * 32;
        // A: direct global (wave covers full 128B lines), fp32 -> bf16 hi/lo
        bf16x8 ah[2], al[2];
        #pragma unroll
        for (int mt = 0; mt < 2; ++mt) {
            const float* ap = stream1e + (mt ? arow1 : arow0) + k0 + lg * 8;
            const float4 v0 = *(const float4*)ap;
            const float4 v1 = *(const float4*)(ap + 4);
            const float f[8] = {v0.x, v0.y, v0.z, v0.w, v1.x, v1.y, v1.z, v1.w};
            int hw[4], lw[4];
            #pragma unroll
            for (int p = 0; p < 4; ++p) {
                unsigned int hp;
                asm("v_cvt_pk_bf16_f32 %0, %1, %2" : "=v"(hp) : "v"(f[2*p]), "v"(f[2*p+1]));
                const float h0 = __uint_as_float(hp << 16);
                const float h1 = __uint_as_float(hp & 0xFFFF0000u);
                const float l0 = f[2*p]   - h0;
                const float l1 = f[2*p+1] - h1;
                unsigned int lp;
                asm("v_cvt_pk_bf16_f32 %0, %1, %2" : "=v"(lp) : "v"(l0), "v"(l1));
                hw[p] = (int)hp;
                lw[p] = (int)lp;
            }
            ah[mt] = *(const bf16x8*)hw;
            al[mt] = *(const bf16x8*)lw;
        }

        const unsigned short* bufp = uni + (kt & 1) * BUF_US;
        const int rot = ((lg + lr) & 3) * 8;
        #pragma unroll
        for (int nt = 0; nt < 8; ++nt) {
            const int rhi = sp * 128 + nt * 16 + lr;      // plane 0 row
            const bf16x8 bh_ = *(const bf16x8*)(bufp + rhi * 32 + rot);
            const bf16x8 bl_ = *(const bf16x8*)(bufp + 8192 + rhi * 32 + rot);
            acc[0][nt] = __builtin_amdgcn_mfma_f32_16x16x32_bf16(ah[0], bh_, acc[0][nt], 0, 0, 0);
            acc[0][nt] = __builtin_amdgcn_mfma_f32_16x16x32_bf16(ah[0], bl_, acc[0][nt], 0, 0, 0);
            acc[0][nt] = __builtin_amdgcn_mfma_f32_16x16x32_bf16(al[0], bh_, acc[0][nt], 0, 0, 0);
            acc[1][nt] = __builtin_amdgcn_mfma_f32_16x16x32_bf16(ah[1], bh_, acc[1][nt], 0, 0, 0);
            acc[1][nt] = __builtin_amdgcn_mfma_f32_16x16x32_bf16(ah[1], bl_, acc[1][nt], 0, 0, 0);
            acc[1][nt] = __builtin_amdgcn_mfma_f32_16x16x32_bf16(al[1], bh_, acc[1][nt], 0, 0, 0);
        }
        __syncthreads();   // readers done with buf[kt&1]; next stage may overwrite
    }

    // ---- epilogue: bias + envelope, write orbitals to this wave's orb tile ----
    // (staging buffers dead; orb aliases them — last barrier above protects)
    const float* pi_s = sp ? pid_ : piu;
    const float* a_s  = sp ? ad   : au;
    const float* b_s  = sp ? bd   : bu;
    float* ow = orb + (size_t)w * ORB_WAVE;
    {
        float dq[2][4][4];
        #pragma unroll
        for (int mt = 0; mt < 2; ++mt)
            #pragma unroll
            for (int q = 0; q < 4; ++q) {
                const int row = mt * 16 + lg * 4 + q;
                const f32x4 dv = *(const f32x4*)&distL[(w * 32 + row) * 4];
                dq[mt][q][0] = dv[0]; dq[mt][q][1] = dv[1];
                dq[mt][q][2] = dv[2]; dq[mt][q][3] = dv[3];
            }
        #pragma unroll
        for (int nt = 0; nt < 8; ++nt) {
            const int C = nt * 16 + lr;
            float pv[4], av[4];
            #pragma unroll
            for (int ion = 0; ion < 4; ++ion) {
                pv[ion] = pi_s[ion * NO + C];
                av[ion] = a_s [ion * NO + C];
            }
            const float bias = b_s[C];
            #pragma unroll
            for (int mt = 0; mt < 2; ++mt)
                #pragma unroll
                for (int q = 0; q < 4; ++q) {
                    float env = 0.f;
                    #pragma unroll
                    for (int ion = 0; ion < 4; ++ion)
                        env += pv[ion] * __expf(-av[ion] * dq[mt][q][ion]);
                    ow[(mt * 16 + lg * 4 + q) * ORW + C] = (acc[mt][nt][q] + bias) * env;
                }
        }
    }
    // same-wave LDS RAW: no barrier

    // ---- per-lane 8x8 slogdet (register LU, conditional-swap pivoting) ----
    {
        const int bl_ = lane >> 4;      // wave-local batch 0..3
        const int dd  = lane & 15;      // determinant index
        float M[8][8];
        #pragma unroll
        for (int e = 0; e < 8; ++e) {
            const float* pr = ow + (bl_ * 8 + e) * ORW + dd * 8;
            const f32x4 u0 = *(const f32x4*)pr;
            const f32x4 u1 = *(const f32x4*)(pr + 4);
            M[e][0] = u0[0]; M[e][1] = u0[1]; M[e][2] = u0[2]; M[e][3] = u0[3];
            M[e][4] = u1[0]; M[e][5] = u1[1]; M[e][6] = u1[2]; M[e][7] = u1[3];
        }
        float ldet = 0.f, sgn = 1.f;
        #pragma unroll
        for (int c = 0; c < 8; ++c) {
            #pragma unroll
            for (int r = c + 1; r < 8; ++r) {
                const bool swp = fabsf(M[r][c]) > fabsf(M[c][c]);
                sgn = swp ? -sgn : sgn;
                #pragma unroll
                for (int j = c; j < 8; ++j) {
                    const float x1 = M[c][j], x2 = M[r][j];
                    M[c][j] = swp ? x2 : x1;
                    M[r][j] = swp ? x1 : x2;
                }
            }
            const float p = M[c][c];
            ldet += __logf(fabsf(p));
            sgn  = (p < 0.f) ? -sgn : sgn;
            const float rp = (p != 0.f) ? (1.0f / p) : 0.f;
            #pragma unroll
            for (int r = c + 1; r < 8; ++r) {
                const float fm = M[r][c] * rp;
                #pragma unroll
                for (int j = c + 1; j < 8; ++j)
                    M[r][j] = fmaf(-fm, M[c][j], M[r][j]);
            }
        }
        const int bb = bh * 4 + bl_;    // block-local batch 0..7
        exL[((sp * 8 + bb) * 16 + dd) * 2 + 0] = ldet;
        exL[((sp * 8 + bb) * 16 + dd) * 2 + 1] = sgn;
    }
    __syncthreads();

    // ---- signed logsumexp over 16 determinants (threads 0..127) ----
    if (t < 128) {
        const int b  = t >> 4;
        const int d2 = t & 15;
        const float lu  = exL[((b)     * 16 + d2) * 2 + 0];
        const float su  = exL[((b)     * 16 + d2) * 2 + 1];
        const float ldn = exL[((8 + b) * 16 + d2) * 2 + 0];
        const float sdn = exL[((8 + b) * 16 + d2) * 2 + 1];
        const float l   = lu + ldn;
        const float s   = su * sdn;
        float m = l;
        #pragma unroll
        for (int off = 1; off <= 8; off <<= 1) m = fmaxf(m, __shfl_xor(m, off));
        float ss = s * __expf(l - m);
        #pragma unroll
        for (int off = 1; off <= 8; off <<= 1) ss += __shfl_xor(ss, off);
        if (d2 == 0) out[b0 + b] = m + __logf(fabsf(ss));
    }
}

extern "C" void kernel_launch(void* const* d_in, const int* in_sizes, int n_in,
                              void* d_out, int out_size, void* d_ws, size_t ws_size,
                              hipStream_t stream) {
    (void)n_in; (void)in_sizes; (void)ws_size;
    const float* s1e  = (const float*)d_in[0];
    const float* r_ei = (const float*)d_in[1];
    const float* Wu   = (const float*)d_in[2];
    const float* bu   = (const float*)d_in[3];
    const float* piu  = (const float*)d_in[4];
    const float* au   = (const float*)d_in[5];
    const float* Wd   = (const float*)d_in[6];
    const float* bd   = (const float*)d_in[7];
    const float* pid_ = (const float*)d_in[8];
    const float* ad   = (const float*)d_in[9];
    float* out = (float*)d_out;
    unsigned short* wt = (unsigned short*)d_ws;   // 256 KB

    hipLaunchKernelGGL(prep_wt, dim3(256), dim3(64), 0, stream, Wu, Wd, wt);

    const int B = out_size;   // 4096
    hipLaunchKernelGGL(fermi_main, dim3(B / 8), dim3(256), 0, stream,
                       s1e, r_ei, bu, piu, au, bd, pid_, ad, wt, out);
}